// Round 2
// baseline (151.689 us; speedup 1.0000x reference)
//
#include <hip/hip_runtime.h>

// StructuredMAPLoss: B=1024 rows, C=128 classes.
// out[0] = loss (mean over classes), out[1 + i*C + c] = ranking[i][c].

constexpr int Bn = 1024;
constexpr int Cn = 128;
constexpr int TPB = 256;
constexpr int SPLIT = 4;            // sub-blocks per class
constexpr int ROWS = Bn / SPLIT;    // rows per sub-block = 256

__device__ __forceinline__ unsigned long long pack3(int f) {
    // valid count in bits[0:21), neg in [21:42), pos in [42:63)
    unsigned long long v = 0;
    if (f != 0) v += 1ull;
    if (f == 2) v += (1ull << 21);
    if (f == 1) v += (1ull << 42);
    return v;
}

__global__ __launch_bounds__(TPB) void map_loss_kernel(
    const float* __restrict__ x,
    const int* __restrict__ tgt,
    const void* __restrict__ maskraw,
    float* __restrict__ out)
{
    __shared__ float xs[Bn];
    __shared__ int rs[Bn];
    __shared__ unsigned char fl[Bn];
    __shared__ unsigned long long wtot[4];
    __shared__ int smode;
    __shared__ float red[5][4];

    const int bx   = blockIdx.x;
    const int c    = bx / SPLIT;
    const int sub  = bx % SPLIT;
    const int tid  = threadIdx.x;
    const int lane = tid & 63;
    const int wid  = tid >> 6;

    // ---- detect mask storage format (bool may arrive as i32 / f32 / u8) ----
    if (tid == 0) {
        const int*   wi = (const int*)maskraw;
        const float* wf = (const float*)maskraw;
        bool okInt = true, okF = true;
        for (int k = 0; k < 32; ++k) {
            int v = wi[k];
            if (v != 0 && v != 1) okInt = false;
            float f = wf[k];
            if (f != 0.0f && f != 1.0f) okF = false;
        }
        smode = okInt ? 0 : (okF ? 1 : 2);
    }
    __syncthreads();
    const int mode = smode;

    // ---- stage column c into LDS ----
    for (int i = tid; i < Bn; i += TPB) {
        int idx = i * Cn + c;
        float xv = x[idx];
        int t = tgt[idx];
        bool m;
        if (mode == 0)      m = ((const int*)maskraw)[idx] != 0;
        else if (mode == 1) m = ((const float*)maskraw)[idx] != 0.0f;
        else                m = ((const unsigned char*)maskraw)[idx] != 0;
        int f = 0;
        if (m) f = (t == 1) ? 1 : ((t == 0) ? 2 : 3);
        xs[i] = xv;
        fl[i] = (unsigned char)f;
    }
    __syncthreads();

    // ---- packed prefix scan of (valid, neg, pos) counts; compute r ----
    unsigned long long local = 0;
    const int base_i = tid * 4;
    #pragma unroll
    for (int k = 0; k < 4; ++k) local += pack3(fl[base_i + k]);

    unsigned long long v = local;
    #pragma unroll
    for (int off = 1; off < 64; off <<= 1) {
        unsigned long long o = __shfl_up(v, off);
        if (lane >= off) v += o;
    }
    if (lane == 63) wtot[wid] = v;
    __syncthreads();
    unsigned long long wpre = 0;
    for (int w = 0; w < wid; ++w) wpre += wtot[w];
    const unsigned long long tot = wtot[0] + wtot[1] + wtot[2] + wtot[3];
    unsigned long long run = wpre + v - local;   // exclusive prefix at base_i

    const int M = (int)(tot & 0x1FFFFF);
    const int N = (int)((tot >> 21) & 0x1FFFFF);
    const int P = (int)((tot >> 42) & 0x1FFFFF);
    const bool active = (P > 0) && (N > 0);

    #pragma unroll
    for (int k = 0; k < 4; ++k) {
        int i = base_i + k;
        int f = fl[i];
        int vb = (int)(run & 0x1FFFFF);
        int nb = (int)((run >> 21) & 0x1FFFFF);
        int pb = (int)((run >> 42) & 0x1FFFFF);
        int mfi = (f != 0) ? 1 : 0;
        int bse = M - mfi - 2 * vb;
        int r;
        if (f == 1)      r = bse + 2 * nb;
        else if (f == 2) r = bse + 2 * pb - 2 * P;
        else             r = bse;
        rs[i] = r;
        run += pack3(f);
    }
    __syncthreads();

    // ---- write ranking rows owned by this sub-block ----
    const int iStart = sub * ROWS;
    {
        int i = iStart + tid;
        float rv = (active && fl[i] != 0) ? (float)rs[i] : 0.0f;
        out[1 + i * Cn + c] = rv;
    }

    // ---- pairwise pass (one row per thread) ----
    float S_ap = 0.f, S_t1 = 0.f, S_t2 = 0.f, S_px = 0.f, S_nx = 0.f;
    {
        const int i = iStart + tid;
        const int f_i = fl[i];
        if (f_i == 1 || f_i == 2) {
            const float xi = xs[i];
            const int ri = rs[i];
            int cntV = 0, cntP = 0, cntNlt = 0, cntPgt = 0;
            #pragma unroll 4
            for (int j = 0; j < Bn; ++j) {
                int fj = fl[j];
                float xj = xs[j];
                int rj = rs[j];
                int g = (xj > xi) || ((xj == xi) && (j < i));
                cntV   += (fj != 0) & g;
                cntP   += (fj == 1) & g;
                cntNlt += (fj == 2) & (rj < ri);
                cntPgt += (fj == 1) & (rj > ri);
            }
            if (f_i == 1) {
                S_ap += (float)(1 + cntP) / (float)(1 + cntV);
                S_t1 += xi * (2.0f * (float)cntNlt - (float)N);
                S_px += xi;
            } else {
                S_t2 += xi * (2.0f * (float)cntPgt - (float)P);
                S_nx += xi;
            }
        }
    }

    // ---- block reduction of the 5 partial sums ----
    #pragma unroll
    for (int off = 32; off > 0; off >>= 1) {
        S_ap += __shfl_down(S_ap, off);
        S_t1 += __shfl_down(S_t1, off);
        S_t2 += __shfl_down(S_t2, off);
        S_px += __shfl_down(S_px, off);
        S_nx += __shfl_down(S_nx, off);
    }
    if (lane == 0) {
        red[0][wid] = S_ap; red[1][wid] = S_t1; red[2][wid] = S_t2;
        red[3][wid] = S_px; red[4][wid] = S_nx;
    }
    __syncthreads();
    if (tid == 0) {
        float apS = red[0][0] + red[0][1] + red[0][2] + red[0][3];
        float t1  = red[1][0] + red[1][1] + red[1][2] + red[1][3];
        float t2  = red[2][0] + red[2][1] + red[2][2] + red[2][3];
        float px  = red[3][0] + red[3][1] + red[3][2] + red[3][3];
        float nx  = red[4][0] + red[4][1] + red[4][2] + red[4][3];
        float contrib = 0.0f;
        if (active) {
            float Pf = (float)P, Nf = (float)N;
            float denom = Pf * Nf + 1e-8f;
            contrib = (sub == 0 ? 1.0f : 0.0f)
                    - apS / (Pf + 1e-8f)
                    + (t1 - t2) / denom
                    - (Nf * px - Pf * nx) / denom;
        }
        atomicAdd(out, contrib * (1.0f / (float)Cn));
    }
}

extern "C" void kernel_launch(void* const* d_in, const int* in_sizes, int n_in,
                              void* d_out, int out_size, void* d_ws, size_t ws_size,
                              hipStream_t stream) {
    const float* x   = (const float*)d_in[0];
    const int*   tgt = (const int*)d_in[1];
    const void*  msk = d_in[2];
    float* out = (float*)d_out;

    hipMemsetAsync(out, 0, sizeof(float), stream);   // zero the loss accumulator
    hipLaunchKernelGGL(map_loss_kernel, dim3(Cn * SPLIT), dim3(TPB), 0, stream,
                       x, tgt, msk, out);
}

// Round 3
// 80.415 us; speedup vs baseline: 1.8863x; 1.8863x over previous
//
#include <hip/hip_runtime.h>

// StructuredMAPLoss: B=1024 rows, C=128 classes.
// out[0] = loss (mean over classes), out[1 + i*C + c] = ranking[i][c].
// One block (1024 threads) per class. O(B log^2 B) via bitonic sort + r-histogram.

constexpr int Bn = 1024;
constexpr int Cn = 128;
constexpr int TPB = 1024;
constexpr int NBINS = 2048;
constexpr int ROFF = 3072;   // bin = (r + ROFF) >> 1 ; r in [-3071, 1023], parity fixed per class

__global__ __launch_bounds__(TPB) void map_loss_kernel(
    const float* __restrict__ x,
    const int* __restrict__ tgt,
    const void* __restrict__ maskraw,
    float* __restrict__ out)
{
    __shared__ unsigned char fl[Bn];                 // 1 KB
    __shared__ unsigned long long keys[Bn];          // 8 KB
    __shared__ unsigned int hist[NBINS];             // 8 KB
    __shared__ unsigned long long wtot[16];
    __shared__ unsigned int hwt[16];
    __shared__ int iwt[16];
    __shared__ float red[5][16];
    __shared__ int smode;

    const int c    = blockIdx.x;
    const int tid  = threadIdx.x;
    const int lane = tid & 63;
    const int wid  = tid >> 6;

    // ---- detect mask storage format (bool may arrive as i32 / f32 / u8) ----
    if (tid == 0) {
        const int*   wi = (const int*)maskraw;
        const float* wf = (const float*)maskraw;
        bool okInt = true, okF = true;
        for (int k = 0; k < 32; ++k) {
            int v = wi[k];
            if (v != 0 && v != 1) okInt = false;
            float f = wf[k];
            if (f != 0.0f && f != 1.0f) okF = false;
        }
        smode = okInt ? 0 : (okF ? 1 : 2);
    }
    __syncthreads();
    const int mode = smode;

    // ---- stage own element (i == tid) ----
    const int gidx = tid * Cn + c;
    const float xv = x[gidx];
    {
        int t = tgt[gidx];
        bool m;
        if (mode == 0)      m = ((const int*)maskraw)[gidx] != 0;
        else if (mode == 1) m = ((const float*)maskraw)[gidx] != 0.0f;
        else                m = ((const unsigned char*)maskraw)[gidx] != 0;
        int f = 0;
        if (m) f = (t == 1) ? 1 : ((t == 0) ? 2 : 3);
        fl[tid] = (unsigned char)f;
    }
    const int f = fl[tid];   // also kept in register below via reload-free path
    // (compiler keeps f from the store value)

    // ---- packed scan of (valid, neg, pos) counts -> r ----
    unsigned long long local =
        (f != 0 ? 1ull : 0ull) + (f == 2 ? (1ull << 21) : 0ull) + (f == 1 ? (1ull << 42) : 0ull);
    unsigned long long v = local;
    #pragma unroll
    for (int off = 1; off < 64; off <<= 1) {
        unsigned long long o = __shfl_up(v, off);
        if (lane >= off) v += o;
    }
    if (lane == 63) wtot[wid] = v;
    __syncthreads();
    unsigned long long wpre = 0, tot = 0;
    for (int w = 0; w < 16; ++w) {
        unsigned long long t = wtot[w];
        if (w < wid) wpre += t;
        tot += t;
    }
    const unsigned long long excl = wpre + v - local;

    const int M = (int)(tot & 0x1FFFFF);
    const int N = (int)((tot >> 21) & 0x1FFFFF);
    const int P = (int)((tot >> 42) & 0x1FFFFF);
    const bool active = (P > 0) && (N > 0);

    const int vb = (int)(excl & 0x1FFFFF);
    const int nb = (int)((excl >> 21) & 0x1FFFFF);
    const int pb = (int)((excl >> 42) & 0x1FFFFF);
    const int mfi = (f != 0) ? 1 : 0;
    const int bse = M - mfi - 2 * vb;
    int r;
    if (f == 1)      r = bse + 2 * nb;
    else if (f == 2) r = bse + 2 * pb - 2 * P;
    else             r = bse;

    // ---- ranking output ----
    out[1 + gidx] = (active && f != 0) ? (float)r : 0.0f;

    // ---- sort keys + histogram init ----
    {
        unsigned int bits = __float_as_uint(xv);
        unsigned int masc = bits ^ ((bits >> 31) ? 0xFFFFFFFFu : 0x80000000u); // ascending-monotone
        unsigned int kw = ~masc;                        // descending-x sorts first in ascending key order
        unsigned long long inv = (f == 0) ? 1ull : 0ull;
        keys[tid] = ((unsigned long long)kw << 11) | (inv << 10) | (unsigned long long)tid;
    }
    hist[tid] = 0u;
    hist[tid + 1024] = 0u;
    __syncthreads();

    // ---- r histogram: pos in high 16 bits, neg in low 16 ----
    if (f == 1)      atomicAdd(&hist[(r + ROFF) >> 1], 1u << 16);
    else if (f == 2) atomicAdd(&hist[(r + ROFF) >> 1], 1u);

    // ---- bitonic sort, ascending, 55 stages ----
    for (int k = 2; k <= Bn; k <<= 1) {
        for (int j = k >> 1; j > 0; j >>= 1) {
            __syncthreads();
            int i = tid;
            int ixj = i ^ j;
            if (ixj > i) {
                unsigned long long a = keys[i];
                unsigned long long b = keys[ixj];
                bool up = ((i & k) == 0);
                if ((a > b) == up) { keys[i] = b; keys[ixj] = a; }
            }
        }
    }
    __syncthreads();

    // ---- packed histogram inclusive prefix scan (2 bins / thread) ----
    {
        unsigned int h0 = hist[2 * tid];
        unsigned int h1 = hist[2 * tid + 1];
        unsigned int hl = h0 + h1;
        unsigned int hv = hl;
        #pragma unroll
        for (int off = 1; off < 64; off <<= 1) {
            unsigned int o = __shfl_up(hv, off);
            if (lane >= off) hv += o;
        }
        if (lane == 63) hwt[wid] = hv;
        __syncthreads();                 // separates hist reads from in-place writes
        unsigned int hpre = 0;
        for (int w = 0; w < wid; ++w) hpre += hwt[w];
        unsigned int hexcl = hpre + hv - hl;
        hist[2 * tid]     = hexcl + h0;
        hist[2 * tid + 1] = hexcl + h0 + h1;
    }

    // ---- cumP over sorted order -> AP contribution ----
    float S_ap = 0.0f;
    {
        unsigned long long kk = keys[tid];
        int sidx = (int)(kk & 0x3FF);
        int ps = (fl[sidx] == 1) ? 1 : 0;
        int pv = ps;
        #pragma unroll
        for (int off = 1; off < 64; off <<= 1) {
            int o = __shfl_up(pv, off);
            if (lane >= off) pv += o;
        }
        if (lane == 63) iwt[wid] = pv;
        __syncthreads();                 // also fences hist writes above
        int ppre = 0;
        for (int w = 0; w < wid; ++w) ppre += iwt[w];
        int cumIncl = ppre + pv;         // inclusive #pos at-or-above sorted pos tid
        if (ps) S_ap = (float)cumIncl / (float)(tid + 1);
    }

    // ---- per-element pairwise terms via histogram lookup ----
    float S_t1 = 0.0f, S_t2 = 0.0f, S_px = 0.0f, S_nx = 0.0f;
    if (f == 1) {
        int rb = (r + ROFF) >> 1;                       // >= 1024, so rb-1 safe
        int cntNlt = (int)(hist[rb - 1] & 0xFFFFu);     // negs with r' < r
        S_t1 = xv * (2.0f * (float)cntNlt - (float)N);
        S_px = xv;
    } else if (f == 2) {
        int rb = (r + ROFF) >> 1;
        int cntPgt = P - (int)(hist[rb] >> 16);         // pos with r' > r
        S_t2 = xv * (2.0f * (float)cntPgt - (float)P);
        S_nx = xv;
    }

    // ---- block reduction of 5 partial sums ----
    #pragma unroll
    for (int off = 32; off > 0; off >>= 1) {
        S_ap += __shfl_down(S_ap, off);
        S_t1 += __shfl_down(S_t1, off);
        S_t2 += __shfl_down(S_t2, off);
        S_px += __shfl_down(S_px, off);
        S_nx += __shfl_down(S_nx, off);
    }
    if (lane == 0) {
        red[0][wid] = S_ap; red[1][wid] = S_t1; red[2][wid] = S_t2;
        red[3][wid] = S_px; red[4][wid] = S_nx;
    }
    __syncthreads();
    if (tid == 0) {
        float apS = 0.f, t1 = 0.f, t2 = 0.f, px = 0.f, nx = 0.f;
        for (int w = 0; w < 16; ++w) {
            apS += red[0][w]; t1 += red[1][w]; t2 += red[2][w];
            px  += red[3][w]; nx += red[4][w];
        }
        float contrib = 0.0f;
        if (active) {
            float Pf = (float)P, Nf = (float)N;
            float denom = Pf * Nf + 1e-8f;
            contrib = 1.0f
                    - apS / (Pf + 1e-8f)
                    + (t1 - t2) / denom
                    - (Nf * px - Pf * nx) / denom;
        }
        atomicAdd(out, contrib * (1.0f / (float)Cn));
    }
}

extern "C" void kernel_launch(void* const* d_in, const int* in_sizes, int n_in,
                              void* d_out, int out_size, void* d_ws, size_t ws_size,
                              hipStream_t stream) {
    const float* x   = (const float*)d_in[0];
    const int*   tgt = (const int*)d_in[1];
    const void*  msk = d_in[2];
    float* out = (float*)d_out;

    hipMemsetAsync(out, 0, sizeof(float), stream);   // zero the loss accumulator
    hipLaunchKernelGGL(map_loss_kernel, dim3(Cn), dim3(TPB), 0, stream,
                       x, tgt, msk, out);
}

// Round 4
// 77.705 us; speedup vs baseline: 1.9521x; 1.0349x over previous
//
#include <hip/hip_runtime.h>

// StructuredMAPLoss: B=1024 rows, C=128 classes.
// out[0] = loss (mean over classes), out[1 + i*C + c] = ranking[i][c].
// One block (1024 threads) per class. Bitonic sort with in-wave shfl stages
// (j<=32) + LDS stages (j>=64 only). r-histogram for pairwise counts.

constexpr int Bn = 1024;
constexpr int Cn = 128;
constexpr int TPB = 1024;
constexpr int NBINS = 2048;
constexpr int ROFF = 3072;   // bin = (r + ROFF) >> 1 ; r in [-3071, 1023], parity fixed per class

__global__ __launch_bounds__(TPB) void map_loss_kernel(
    const float* __restrict__ x,
    const int* __restrict__ tgt,
    const void* __restrict__ maskraw,
    float* __restrict__ out)
{
    __shared__ unsigned char fl[Bn];                 // 1 KB
    __shared__ unsigned long long keys[Bn];          // 8 KB
    __shared__ unsigned int hist[NBINS];             // 8 KB
    __shared__ unsigned long long wtot[16];
    __shared__ unsigned int hwt[16];
    __shared__ int iwt[16];
    __shared__ float red[5][16];
    __shared__ int smode;

    const int c    = blockIdx.x;
    const int tid  = threadIdx.x;
    const int lane = tid & 63;
    const int wid  = tid >> 6;

    // ---- detect mask storage format (bool may arrive as i32 / f32 / u8) ----
    if (tid == 0) {
        const int*   wi = (const int*)maskraw;
        const float* wf = (const float*)maskraw;
        bool okInt = true, okF = true;
        for (int k = 0; k < 32; ++k) {
            int v = wi[k];
            if (v != 0 && v != 1) okInt = false;
            float f = wf[k];
            if (f != 0.0f && f != 1.0f) okF = false;
        }
        smode = okInt ? 0 : (okF ? 1 : 2);
    }
    __syncthreads();
    const int mode = smode;

    // ---- stage own element (i == tid) ----
    const int gidx = tid * Cn + c;
    const float xv = x[gidx];
    int f;
    {
        int t = tgt[gidx];
        bool m;
        if (mode == 0)      m = ((const int*)maskraw)[gidx] != 0;
        else if (mode == 1) m = ((const float*)maskraw)[gidx] != 0.0f;
        else                m = ((const unsigned char*)maskraw)[gidx] != 0;
        f = 0;
        if (m) f = (t == 1) ? 1 : ((t == 0) ? 2 : 3);
        fl[tid] = (unsigned char)f;
    }

    // ---- packed scan of (valid, neg, pos) counts -> r ----
    unsigned long long local =
        (f != 0 ? 1ull : 0ull) + (f == 2 ? (1ull << 21) : 0ull) + (f == 1 ? (1ull << 42) : 0ull);
    unsigned long long v = local;
    #pragma unroll
    for (int off = 1; off < 64; off <<= 1) {
        unsigned long long o = __shfl_up(v, off);
        if (lane >= off) v += o;
    }
    if (lane == 63) wtot[wid] = v;
    __syncthreads();
    unsigned long long wpre = 0, tot = 0;
    for (int w = 0; w < 16; ++w) {
        unsigned long long t = wtot[w];
        if (w < wid) wpre += t;
        tot += t;
    }
    const unsigned long long excl = wpre + v - local;

    const int M = (int)(tot & 0x1FFFFF);
    const int N = (int)((tot >> 21) & 0x1FFFFF);
    const int P = (int)((tot >> 42) & 0x1FFFFF);
    const bool active = (P > 0) && (N > 0);

    const int vb = (int)(excl & 0x1FFFFF);
    const int nb = (int)((excl >> 21) & 0x1FFFFF);
    const int pb = (int)((excl >> 42) & 0x1FFFFF);
    const int mfi = (f != 0) ? 1 : 0;
    const int bse = M - mfi - 2 * vb;
    int r;
    if (f == 1)      r = bse + 2 * nb;
    else if (f == 2) r = bse + 2 * pb - 2 * P;
    else             r = bse;

    // ---- ranking output ----
    out[1 + gidx] = (active && f != 0) ? (float)r : 0.0f;

    // ---- build sort key: invalid flag ABOVE the x key so invalids go last ----
    unsigned long long kr;
    {
        unsigned int bits = __float_as_uint(xv);
        unsigned int masc = bits ^ ((bits >> 31) ? 0xFFFFFFFFu : 0x80000000u); // ascending-monotone
        unsigned int kw = ~masc;                        // descending-x sorts first ascending
        unsigned long long inv = (f == 0) ? 1ull : 0ull;
        kr = (inv << 42) | ((unsigned long long)kw << 10) | (unsigned long long)tid;
    }
    hist[tid] = 0u;
    hist[tid + 1024] = 0u;
    __syncthreads();

    // ---- r histogram: pos in high 16 bits, neg in low 16 ----
    if (f == 1)      atomicAdd(&hist[(r + ROFF) >> 1], 1u << 16);
    else if (f == 2) atomicAdd(&hist[(r + ROFF) >> 1], 1u);

    // ---- bitonic sort, ascending; j<=32 via shfl_xor (in-wave), j>=64 via LDS ----
    #pragma unroll
    for (int k = 2; k <= 64; k <<= 1) {
        for (int j = k >> 1; j > 0; j >>= 1) {
            unsigned long long o = __shfl_xor(kr, j);
            bool keepmin = (((tid & k) == 0) == ((tid & j) == 0));
            kr = ((kr < o) == keepmin) ? kr : o;
        }
    }
    for (int k = 128; k <= 1024; k <<= 1) {
        for (int j = k >> 1; j >= 64; j >>= 1) {
            keys[tid] = kr;
            __syncthreads();
            unsigned long long o = keys[tid ^ j];
            bool keepmin = (((tid & k) == 0) == ((tid & j) == 0));
            kr = ((kr < o) == keepmin) ? kr : o;
            __syncthreads();
        }
        #pragma unroll
        for (int j = 32; j > 0; j >>= 1) {
            unsigned long long o = __shfl_xor(kr, j);
            bool keepmin = (((tid & k) == 0) == ((tid & j) == 0));
            kr = ((kr < o) == keepmin) ? kr : o;
        }
    }
    // kr = key of sorted position tid (valids by descending x first, invalids last)

    // ---- packed histogram inclusive prefix scan (2 bins / thread) ----
    {
        unsigned int h0 = hist[2 * tid];
        unsigned int h1 = hist[2 * tid + 1];
        unsigned int hl = h0 + h1;
        unsigned int hv = hl;
        #pragma unroll
        for (int off = 1; off < 64; off <<= 1) {
            unsigned int o = __shfl_up(hv, off);
            if (lane >= off) hv += o;
        }
        if (lane == 63) hwt[wid] = hv;
        __syncthreads();
        unsigned int hpre = 0;
        for (int w = 0; w < wid; ++w) hpre += hwt[w];
        unsigned int hexcl = hpre + hv - hl;
        hist[2 * tid]     = hexcl + h0;
        hist[2 * tid + 1] = hexcl + h0 + h1;
    }

    // ---- cumP over sorted order -> AP contribution ----
    float S_ap = 0.0f;
    {
        int sidx = (int)(kr & 0x3FF);
        int ps = (fl[sidx] == 1) ? 1 : 0;
        int pv = ps;
        #pragma unroll
        for (int off = 1; off < 64; off <<= 1) {
            int o = __shfl_up(pv, off);
            if (lane >= off) pv += o;
        }
        if (lane == 63) iwt[wid] = pv;
        __syncthreads();                 // fences iwt AND hist writes above
        int ppre = 0;
        for (int w = 0; w < wid; ++w) ppre += iwt[w];
        int cumIncl = ppre + pv;         // inclusive #pos at-or-above sorted pos tid
        if (ps) S_ap = (float)cumIncl / (float)(tid + 1);
    }

    // ---- per-element pairwise terms via histogram lookup ----
    float S_t1 = 0.0f, S_t2 = 0.0f, S_px = 0.0f, S_nx = 0.0f;
    if (f == 1) {
        int rb = (r + ROFF) >> 1;                       // >= 1024, so rb-1 safe
        int cntNlt = (int)(hist[rb - 1] & 0xFFFFu);     // negs with r' < r
        S_t1 = xv * (2.0f * (float)cntNlt - (float)N);
        S_px = xv;
    } else if (f == 2) {
        int rb = (r + ROFF) >> 1;
        int cntPgt = P - (int)(hist[rb] >> 16);         // pos with r' > r
        S_t2 = xv * (2.0f * (float)cntPgt - (float)P);
        S_nx = xv;
    }

    // ---- block reduction of 5 partial sums ----
    #pragma unroll
    for (int off = 32; off > 0; off >>= 1) {
        S_ap += __shfl_down(S_ap, off);
        S_t1 += __shfl_down(S_t1, off);
        S_t2 += __shfl_down(S_t2, off);
        S_px += __shfl_down(S_px, off);
        S_nx += __shfl_down(S_nx, off);
    }
    if (lane == 0) {
        red[0][wid] = S_ap; red[1][wid] = S_t1; red[2][wid] = S_t2;
        red[3][wid] = S_px; red[4][wid] = S_nx;
    }
    __syncthreads();
    if (tid == 0) {
        float apS = 0.f, t1 = 0.f, t2 = 0.f, px = 0.f, nx = 0.f;
        for (int w = 0; w < 16; ++w) {
            apS += red[0][w]; t1 += red[1][w]; t2 += red[2][w];
            px  += red[3][w]; nx += red[4][w];
        }
        float contrib = 0.0f;
        if (active) {
            float Pf = (float)P, Nf = (float)N;
            float denom = Pf * Nf + 1e-8f;
            contrib = 1.0f
                    - apS / (Pf + 1e-8f)
                    + (t1 - t2) / denom
                    - (Nf * px - Pf * nx) / denom;
        }
        atomicAdd(out, contrib * (1.0f / (float)Cn));
    }
}

extern "C" void kernel_launch(void* const* d_in, const int* in_sizes, int n_in,
                              void* d_out, int out_size, void* d_ws, size_t ws_size,
                              hipStream_t stream) {
    const float* x   = (const float*)d_in[0];
    const int*   tgt = (const int*)d_in[1];
    const void*  msk = d_in[2];
    float* out = (float*)d_out;

    hipMemsetAsync(out, 0, sizeof(float), stream);   // zero the loss accumulator
    hipLaunchKernelGGL(map_loss_kernel, dim3(Cn), dim3(TPB), 0, stream,
                       x, tgt, msk, out);
}

// Round 5
// 74.613 us; speedup vs baseline: 2.0330x; 1.0414x over previous
//
#include <hip/hip_runtime.h>

// StructuredMAPLoss: B=1024 rows, C=128 classes.
// out[0] = loss (mean over classes), out[1 + i*C + c] = ranking[i][c].
// One block (512 threads, 2 elements/thread) per class.
// Bitonic sort: j==1 in-register, j=2..64 via shfl_xor, j>=128 via
// double-buffered LDS (1 barrier/stage). r-histogram for pairwise counts.

constexpr int Bn = 1024;
constexpr int Cn = 128;
constexpr int TPB = 512;
constexpr int E = 2;
constexpr int NBINS = 2048;
constexpr int ROFF = 3072;   // bin = (r + ROFF) >> 1 ; valid r in [-3071, 1023], parity fixed

__device__ __forceinline__ unsigned long long pk3(int ff) {
    return (ff != 0 ? 1ull : 0ull) + (ff == 2 ? (1ull << 21) : 0ull) + (ff == 1 ? (1ull << 42) : 0ull);
}

__global__ __launch_bounds__(TPB) void map_loss_kernel(
    const float* __restrict__ x,
    const int* __restrict__ tgt,
    const void* __restrict__ maskraw,
    float* __restrict__ out)
{
    __shared__ unsigned char fl[Bn];                 // 1 KB
    __shared__ unsigned long long kbuf[2][Bn];       // 16 KB (double buffer)
    __shared__ unsigned int hist[NBINS];             // 8 KB
    __shared__ unsigned long long wtot[8];
    __shared__ unsigned int hwt[8];
    __shared__ int iwt[8];
    __shared__ float red[5][8];
    __shared__ int smode;

    const int c    = blockIdx.x;
    const int tid  = threadIdx.x;
    const int lane = tid & 63;
    const int wid  = tid >> 6;

    // ---- detect mask storage format (bool may arrive as i32 / f32 / u8) ----
    if (tid == 0) {
        const int*   wi = (const int*)maskraw;
        const float* wf = (const float*)maskraw;
        bool okInt = true, okF = true;
        for (int k = 0; k < 32; ++k) {
            int v = wi[k];
            if (v != 0 && v != 1) okInt = false;
            float fv = wf[k];
            if (fv != 0.0f && fv != 1.0f) okF = false;
        }
        smode = okInt ? 0 : (okF ? 1 : 2);
    }
    __syncthreads();                                 // B1
    const int mode = smode;

    // ---- load 2 elements / thread; zero histogram ----
    float xv[E]; int f[E];
    #pragma unroll
    for (int e = 0; e < E; ++e) {
        const int i = tid * E + e;
        const int g = i * Cn + c;
        xv[e] = x[g];
        int t = tgt[g];
        bool m;
        if (mode == 0)      m = ((const int*)maskraw)[g] != 0;
        else if (mode == 1) m = ((const float*)maskraw)[g] != 0.0f;
        else                m = ((const unsigned char*)maskraw)[g] != 0;
        f[e] = m ? ((t == 1) ? 1 : ((t == 0) ? 2 : 3)) : 0;
        fl[i] = (unsigned char)f[e];
    }
    #pragma unroll
    for (int q = 0; q < NBINS / TPB; ++q) hist[tid * (NBINS / TPB) + q] = 0u;

    // ---- packed (valid,neg,pos) prefix scan over element order ----
    unsigned long long local = pk3(f[0]) + pk3(f[1]);
    unsigned long long v = local;
    #pragma unroll
    for (int off = 1; off < 64; off <<= 1) {
        unsigned long long o = __shfl_up(v, off);
        if (lane >= off) v += o;
    }
    if (lane == 63) wtot[wid] = v;
    __syncthreads();                                 // B2 (also fences fl + hist zero)
    unsigned long long wpre = 0, tot = 0;
    #pragma unroll
    for (int w = 0; w < 8; ++w) {
        unsigned long long t = wtot[w];
        if (w < wid) wpre += t;
        tot += t;
    }
    unsigned long long run = wpre + v - local;       // exclusive prefix at i = tid*E

    const int M = (int)(tot & 0x1FFFFF);
    const int N = (int)((tot >> 21) & 0x1FFFFF);
    const int P = (int)((tot >> 42) & 0x1FFFFF);
    const bool active = (P > 0) && (N > 0);

    // ---- r closed form, ranking write, histogram atomics, sort keys ----
    int r[E];
    unsigned long long kr[E];
    #pragma unroll
    for (int e = 0; e < E; ++e) {
        const int i = tid * E + e;
        const int vb = (int)(run & 0x1FFFFF);
        const int nb = (int)((run >> 21) & 0x1FFFFF);
        const int pb = (int)((run >> 42) & 0x1FFFFF);
        const int mfi = (f[e] != 0) ? 1 : 0;
        const int bse = M - mfi - 2 * vb;
        r[e] = (f[e] == 1) ? bse + 2 * nb
             : ((f[e] == 2) ? bse + 2 * pb - 2 * P : bse);
        run += pk3(f[e]);

        out[1 + i * Cn + c] = (active && f[e] != 0) ? (float)r[e] : 0.0f;

        if (f[e] == 1)      atomicAdd(&hist[(r[e] + ROFF) >> 1], 1u << 16);
        else if (f[e] == 2) atomicAdd(&hist[(r[e] + ROFF) >> 1], 1u);

        unsigned int bits = __float_as_uint(xv[e]);
        unsigned int masc = bits ^ ((bits >> 31) ? 0xFFFFFFFFu : 0x80000000u);
        unsigned int kw = ~masc;                     // descending-x sorts first ascending
        unsigned long long inv = (f[e] == 0) ? 1ull : 0ull;
        kr[e] = (inv << 42) | ((unsigned long long)kw << 10) | (unsigned long long)i;
    }

    // ---- bitonic sort (ascending): j==1 in-reg, j=2..64 shfl, j>=128 LDS ----
    int lb = 0;
    #pragma unroll
    for (int k = 2; k <= Bn; k <<= 1) {
        #pragma unroll
        for (int j = k >> 1; j > 0; j >>= 1) {
            if (j >= 128) {
                kbuf[lb][tid * E]     = kr[0];
                kbuf[lb][tid * E + 1] = kr[1];
                __syncthreads();                     // 6 of these total
                const int ptid = tid ^ (j >> 1);
                #pragma unroll
                for (int e = 0; e < E; ++e) {
                    unsigned long long o = kbuf[lb][ptid * E + e];
                    const int i = tid * E + e;
                    bool keepmin = ((i & k) == 0) == ((i & j) == 0);
                    kr[e] = ((kr[e] < o) == keepmin) ? kr[e] : o;
                }
                lb ^= 1;                             // WAR safe: next write to this buf
            } else if (j >= E) {                     //   is >=2 barriers away
                const int jl = j >> 1;               // lane distance 1..32
                #pragma unroll
                for (int e = 0; e < E; ++e) {
                    unsigned long long o = __shfl_xor(kr[e], jl);
                    const int i = tid * E + e;
                    bool keepmin = ((i & k) == 0) == ((i & j) == 0);
                    kr[e] = ((kr[e] < o) == keepmin) ? kr[e] : o;
                }
            } else {                                 // j == 1: within thread
                const int i0 = tid * E;
                bool up = ((i0 & k) == 0);
                unsigned long long a = kr[0], b = kr[1];
                bool sw = ((a > b) == up);
                kr[0] = sw ? b : a;
                kr[1] = sw ? a : b;
            }
        }
    }
    // kr[e] = key at sorted position i = tid*E+e (valids desc-x first, invalids last)

    // ---- histogram inclusive scan (4 bins/thread) + AP pos-indicator scan ----
    unsigned int h[NBINS / TPB]; unsigned int hl = 0;
    #pragma unroll
    for (int q = 0; q < NBINS / TPB; ++q) { h[q] = hist[tid * (NBINS / TPB) + q]; hl += h[q]; }
    unsigned int hv = hl;
    #pragma unroll
    for (int off = 1; off < 64; off <<= 1) {
        unsigned int o = __shfl_up(hv, off);
        if (lane >= off) hv += o;
    }
    if (lane == 63) hwt[wid] = hv;

    int ps[E]; int pl = 0;
    #pragma unroll
    for (int e = 0; e < E; ++e) { ps[e] = (fl[kr[e] & 0x3FF] == 1) ? 1 : 0; pl += ps[e]; }
    int pv = pl;
    #pragma unroll
    for (int off = 1; off < 64; off <<= 1) {
        int o = __shfl_up(pv, off);
        if (lane >= off) pv += o;
    }
    if (lane == 63) iwt[wid] = pv;
    __syncthreads();                                 // A: hwt + iwt ready

    unsigned int hpre = 0; int ppre = 0;
    #pragma unroll
    for (int w = 0; w < 8; ++w) {
        if (w < wid) { hpre += hwt[w]; ppre += iwt[w]; }
    }
    unsigned int hrun = hpre + hv - hl;
    #pragma unroll
    for (int q = 0; q < NBINS / TPB; ++q) { hrun += h[q]; hist[tid * (NBINS / TPB) + q] = hrun; }

    float S_ap = 0.0f;
    int prun = ppre + pv - pl;
    #pragma unroll
    for (int e = 0; e < E; ++e) {
        prun += ps[e];
        if (ps[e]) S_ap += (float)prun / (float)(tid * E + e + 1);
    }
    __syncthreads();                                 // B: inclusive hist visible

    // ---- per-element pairwise terms via histogram lookup ----
    float S_t1 = 0.0f, S_t2 = 0.0f, S_px = 0.0f, S_nx = 0.0f;
    #pragma unroll
    for (int e = 0; e < E; ++e) {
        if (f[e] == 1) {
            int rb = (r[e] + ROFF) >> 1;             // >= 1024, rb-1 safe
            int cnt = (int)(hist[rb - 1] & 0xFFFFu); // negs with r' < r
            S_t1 += xv[e] * (2.0f * (float)cnt - (float)N);
            S_px += xv[e];
        } else if (f[e] == 2) {
            int rb = (r[e] + ROFF) >> 1;
            int cnt = P - (int)(hist[rb] >> 16);     // pos with r' > r
            S_t2 += xv[e] * (2.0f * (float)cnt - (float)P);
            S_nx += xv[e];
        }
    }

    // ---- block reduction of 5 partial sums ----
    #pragma unroll
    for (int off = 32; off > 0; off >>= 1) {
        S_ap += __shfl_down(S_ap, off);
        S_t1 += __shfl_down(S_t1, off);
        S_t2 += __shfl_down(S_t2, off);
        S_px += __shfl_down(S_px, off);
        S_nx += __shfl_down(S_nx, off);
    }
    if (lane == 0) {
        red[0][wid] = S_ap; red[1][wid] = S_t1; red[2][wid] = S_t2;
        red[3][wid] = S_px; red[4][wid] = S_nx;
    }
    __syncthreads();
    if (tid == 0) {
        float apS = 0.f, t1 = 0.f, t2 = 0.f, px = 0.f, nx = 0.f;
        #pragma unroll
        for (int w = 0; w < 8; ++w) {
            apS += red[0][w]; t1 += red[1][w]; t2 += red[2][w];
            px  += red[3][w]; nx += red[4][w];
        }
        float contrib = 0.0f;
        if (active) {
            float Pf = (float)P, Nf = (float)N;
            float denom = Pf * Nf + 1e-8f;
            contrib = 1.0f
                    - apS / (Pf + 1e-8f)
                    + (t1 - t2) / denom
                    - (Nf * px - Pf * nx) / denom;
        }
        atomicAdd(out, contrib * (1.0f / (float)Cn));
    }
}

extern "C" void kernel_launch(void* const* d_in, const int* in_sizes, int n_in,
                              void* d_out, int out_size, void* d_ws, size_t ws_size,
                              hipStream_t stream) {
    const float* x   = (const float*)d_in[0];
    const int*   tgt = (const int*)d_in[1];
    const void*  msk = d_in[2];
    float* out = (float*)d_out;

    hipMemsetAsync(out, 0, sizeof(float), stream);   // zero the loss accumulator
    hipLaunchKernelGGL(map_loss_kernel, dim3(Cn), dim3(TPB), 0, stream,
                       x, tgt, msk, out);
}